// Round 8
// baseline (19.466 us; speedup 1.0000x reference)
//
#include <hip/hip_runtime.h>

#define NN 2048

typedef float f32x2 __attribute__((ext_vector_type(2)));

__device__ __forceinline__ f32x2 cub2(f32x2 px, f32x2 py, f32x2 b0, f32x2 b1, f32x2 b2) {
    // b0*px^3 + b1*px^2*py + b2*px*py^2, elementwise (v_pk_fma/v_pk_mul)
    return px * (px * (px * b0 + py * b1) + (py * py) * b2);
}

// One channel = 2 pairs: multiplicative-FD state E,G,H,K and float trip bound nf.
struct Chan { f32x2 E, G, H, K, nf; };

__device__ __forceinline__ Chan make_chan(float X, float Y, float4 xj,
                                          float p0, float p1, float p2,
                                          float p3, float p4, float p5) {
    const float NL  = -1.4426950408889634f;   // -log2(e)
    const float NL3 = -4.3280851226668903f;   // -3*log2(e) (comb folded)

    f32x2 dx = {xj.x - X, xj.z - X};
    f32x2 dy = {xj.y - Y, xj.w - Y};
    f32x2 d2 = dx * dx + dy * dy;
    f32x2 dist = { __builtin_amdgcn_sqrtf(d2.x), __builtin_amdgcn_sqrtf(d2.y) };
    f32x2 sf = { dist.x > 0.0f ? __builtin_amdgcn_rcpf(dist.x) * 0.1f : 0.0f,
                 dist.y > 0.0f ? __builtin_amdgcn_rcpf(dist.y) * 0.1f : 0.0f };
    f32x2 ux = dx * sf, uy = dy * sf;

    Chan c;
    // n = floor(dist*10) <= 14 always (dist <= sqrt(2)), no clamp needed
    c.nf = { floorf(dist.x * 10.0f), floorf(dist.y * 10.0f) };

    f32x2 b0 = NL  * (p0 * dx + p1 * dy);
    f32x2 b1 = NL3 * (p2 * dx + p3 * dy);
    f32x2 b2 = NL3 * (p4 * dx + p5 * dy);

    f32x2 Xv = {X, X}, Yv = {Y, Y};
    f32x2 x1 = Xv + ux,  y1 = Yv + uy;
    f32x2 x2 = x1 + ux,  y2 = y1 + uy;
    f32x2 f0 = cub2(Xv, Yv, b0, b1, b2);
    f32x2 f1 = cub2(x1, y1, b0, b1, b2);
    f32x2 f2 = cub2(x2, y2, b0, b1, b2);
    f32x2 c3 = cub2(ux, uy, b0, b1, b2);

    f32x2 d1 = f1 - f0;
    f32x2 dd = (f2 - 2.0f * f1) + f0;
    f32x2 d3 = 6.0f * c3;

    c.E = { __builtin_amdgcn_exp2f(f0.x), __builtin_amdgcn_exp2f(f0.y) };
    c.G = { __builtin_amdgcn_exp2f(d1.x), __builtin_amdgcn_exp2f(d1.y) };
    c.H = { __builtin_amdgcn_exp2f(dd.x), __builtin_amdgcn_exp2f(dd.y) };
    c.K = { __builtin_amdgcn_exp2f(d3.x), __builtin_amdgcn_exp2f(d3.y) };
    return c;
}

__global__ __launch_bounds__(256, 8) void FlowEmbedder_kernel(
    const float* __restrict__ x,      // [N,2]
    const float* __restrict__ p,      // [3,2]
    float* __restrict__ out)          // [N,N]
{
    int tid = blockIdx.x * 256 + threadIdx.x;   // 4 outputs per thread
    int i  = tid >> 9;                           // row (512 threads per row)
    int j4 = tid & 511;                          // group of 4 columns

    float2 xi  = ((const float2*)x)[i];
    float4 xjC = ((const float4*)x)[2 * j4];     // cols 4j4, 4j4+1
    float4 xjD = ((const float4*)x)[2 * j4 + 1]; // cols 4j4+2, 4j4+3

    float p0 = p[0], p1 = p[1], p2 = p[2], p3 = p[3], p4 = p[4], p5 = p[5];

    Chan C = make_chan(xi.x, xi.y, xjC, p0, p1, p2, p3, p4, p5);
    Chan D = make_chan(xi.x, xi.y, xjD, p0, p1, p2, p3, p4, p5);

    // Fixed 15 trips (n <= 14 for every pair), fully unrolled, branch-free.
    f32x2 sC = {0.0f, 0.0f}, sD = {0.0f, 0.0f};
    #pragma unroll
    for (int t = 0; t < 15; ++t) {
        float tf = (float)t;                     // literal per unrolled iter
        f32x2 mC, mD;                            // cndmask on E: inf/NaN-safe tail
        mC.x = (tf <= C.nf.x) ? C.E.x : 0.0f;
        mC.y = (tf <= C.nf.y) ? C.E.y : 0.0f;
        mD.x = (tf <= D.nf.x) ? D.E.x : 0.0f;
        mD.y = (tf <= D.nf.y) ? D.E.y : 0.0f;
        sC += mC;                                // v_pk_add_f32
        sD += mD;
        if (t < 14) {                            // last-iter updates are dead
            C.E *= C.G; C.G *= C.H; C.H *= C.K;  // 6 × v_pk_mul_f32
            D.E *= D.G; D.G *= D.H; D.H *= D.K;
        }
    }

    // cost = 0.02*(n+1) + 0.08*sum_exp  (packed epilogue)
    f32x2 cc = 0.02f * C.nf + 0.02f + 0.08f * sC;
    f32x2 cd = 0.02f * D.nf + 0.02f + 0.08f * sD;
    float4 res = { cc.x, cc.y, cd.x, cd.y };
    ((float4*)out)[tid] = res;
}

extern "C" void kernel_launch(void* const* d_in, const int* in_sizes, int n_in,
                              void* d_out, int out_size, void* d_ws, size_t ws_size,
                              hipStream_t stream) {
    const float* x = (const float*)d_in[0];   // embedded_points [2048,2]
    const float* p = (const float*)d_in[1];   // flow_field_parameters [3,2]
    float* out = (float*)d_out;               // [2048,2048]

    const int total_threads = NN * NN / 4;    // 4 outputs per thread
    FlowEmbedder_kernel<<<total_threads / 256, 256, 0, stream>>>(x, p, out);
}